// Round 10
// baseline (285.757 us; speedup 1.0000x reference)
//
#include <hip/hip_runtime.h>
#include <cmath>

// Shapes fixed by reference: R=4096, F=256, K=8.
#define R 4096
#define F 256
#define NK 8

typedef _Float16 half8 __attribute__((ext_vector_type(8)));
typedef _Float16 half4v __attribute__((ext_vector_type(4)));
typedef float f32x4 __attribute__((ext_vector_type(4)));

#define LOG2E      1.4426950408889634f
#define LOG2LOG2E  0.5287663729448977f   // log2(log2(e))

// ---------------------------------------------------------------------------
// ws layout (bytes):
//   0          : x1h (4096*256 f16) 2 MB
//   2 MB       : x2h (4096*256 f16) 2 MB
//   4 MB +0    : S   (8*4096 f32)  softmax denominators (phase-0 atomics)
//       +128K  : rA  (8*4096 f32)  c_k*(sq1-2m r1+Fm^2)+log2log2e
//       +256K  : cB  (8*4096 f32)  c_k*(sq2+2m r2)
//       +384K  : prm (16 f32) [0..7]=w_k  [8..15]=g_k = 2*is2*log2e
// Math: c_k = -log2e/(2 s_k^2); t = rA[k][i]+cB[k][j]+g_k*dot,  g_k = -2 c_k
//       exp(kv) = exp2(exp2(t)).  dist in [~150,~6600] so ref clamps never bind.
//
// Structure: two-GEMM. R10: 128x64 tile, 4 waves of 32x64, acc[2][4] = 32
// AGPR -> unified ~96-102 regs -> __launch_bounds__(256,5) = 5 blocks/CU
// (was 2). The phases are latency-bound at 2 waves/SIMD (R9 falsified the
// L2-miss theory: FETCH unchanged by swizzle); more waves hide the exp2
// chains and staging latency.
// FAILED -- do not reintroduce:
//  * cooperative grid.sync fusion (R1): +380 MB HBM spin/coherence traffic.
//  * dot spill through `out` (R2/R4): 64 MB writes back to HBM either way.
//  * NT stores (R2): write-drain stall, +29us.
//  * global_load_lds staging (R6): +16 VGPR -> occupancy cliff. Bank
//    conflicts are a non-issue (2-way alias free; 1e6->0 was worth ~0).
//  * phase1 epilogue k-outer vectorization (R7): +7us (live-set growth).
//  * XCD block swizzle (R9): FETCH unchanged, +3us. Not cache-miss-bound.
// ---------------------------------------------------------------------------

__global__ __launch_bounds__(256) void prep_kernel(
    const float* __restrict__ x1, const float* __restrict__ x2,
    const float* __restrict__ sigmas, const float* __restrict__ means,
    const float* __restrict__ sigp,
    _Float16* __restrict__ x1h, _Float16* __restrict__ x2h,
    float* __restrict__ rA, float* __restrict__ cB,
    float* __restrict__ S, float* __restrict__ prm)
{
    const int tid  = threadIdx.x;
    const int wid  = tid >> 6;
    const int lane = tid & 63;
    const int row  = blockIdx.x * 4 + wid;   // 0..8191: x1 rows then x2 rows

    const float* src; _Float16* dsth; int r; bool isX1;
    if (row < R) { src = x1; dsth = x1h; r = row;     isX1 = true;  }
    else         { src = x2; dsth = x2h; r = row - R; isX1 = false; }

    float4 v = ((const float4*)(src + (size_t)r * F))[lane];
    half4v h = { (_Float16)v.x, (_Float16)v.y, (_Float16)v.z, (_Float16)v.w };
    *(half4v*)(dsth + (size_t)r * F + lane * 4) = h;

    float s = v.x + v.y + v.z + v.w;
    float q = v.x * v.x + v.y * v.y + v.z * v.z + v.w * v.w;
    for (int m = 1; m < 64; m <<= 1) {
        s += __shfl_xor(s, m);
        q += __shfl_xor(q, m);
    }
    if (lane < NK) {
        int k = lane;
        float sg = sigmas[k], m = means[k];
        float c  = -LOG2E / (2.f * sg * sg);         // c_k
        if (isX1) rA[k * R + r] = c * (q - 2.f * m * s + (float)F * m * m) + LOG2LOG2E;
        else      cB[k * R + r] = c * (q + 2.f * m * s);
    }

    int g = blockIdx.x * 256 + tid;
    if (g < NK * R) S[g] = 0.f;   // ws re-poisoned 0xAA each call

    if (blockIdx.x == 0 && tid == 0) {
        float w[NK], mx = -1e30f;
        for (int k = 0; k < NK; ++k) { float sp = sigp[k]; w[k] = 1.f / (sp * sp); mx = fmaxf(mx, w[k]); }
        float sum = 0.f;
        for (int k = 0; k < NK; ++k) { w[k] = expf(w[k] - mx); sum += w[k]; }
        for (int k = 0; k < NK; ++k) prm[k] = w[k] / sum;
        for (int k = 0; k < NK; ++k) {
            float sg = sigmas[k];
            prm[8 + k] = LOG2E / (sg * sg);     // g_k = 2*is2*log2e
        }
    }
}

// DPP-fused add: x + dpp_move(x, CTRL). CTRL must be an ICE -> template arg.
// Folds to v_add_f32_dpp (full-rate VALU, no lgkm). Verified bit-identical
// to the shfl reduce (R4/R5).
template <int CTRL>
__device__ __forceinline__ float dpp_radd(float x) {
    int xi = __builtin_bit_cast(int, x);
    int yi = __builtin_amdgcn_update_dpp(0, xi, CTRL, 0xF, 0xF, true);
    return x + __builtin_bit_cast(float, yi);
}

// ---------------------------------------------------------------------------
// Shared GEMM body (R10): 128x64 tile, 4 waves each owning a 32x64 strip.
// acc[2][4] = 32 f32/thread. Reg-staged LDS, SK=72 pad (2-way alias, free).
// A-tile 128x64 halves (18.4KB), B-tile 64x64 halves (9.2KB) -> 27.6KB.
// ---------------------------------------------------------------------------
#define GEMM_BODY                                                             \
    constexpr int SK = 72;                                                    \
    __shared__ _Float16 As[128 * SK];                                         \
    __shared__ _Float16 Bs[64 * SK];                                          \
    const int tid  = threadIdx.x;                                             \
    const int lane = tid & 63;                                                \
    const int wid  = tid >> 6;       /* wave -> 32-row strip */               \
    const int q    = lane >> 4, m16 = lane & 15;                              \
    const int tm   = blockIdx.y, tn = blockIdx.x;                             \
    f32x4 acc[2][4];                                                          \
    _Pragma("unroll")                                                         \
    for (int a = 0; a < 2; ++a)                                               \
        _Pragma("unroll")                                                     \
        for (int b = 0; b < 4; ++b)                                           \
            acc[a][b] = (f32x4){0.f, 0.f, 0.f, 0.f};                          \
    for (int k0 = 0; k0 < F; k0 += 64) {                                      \
        _Pragma("unroll")                                                     \
        for (int c = 0; c < 4; ++c) {   /* A: 4x32 rows */                    \
            int idx = c * 256 + tid;                                          \
            int row = idx >> 3, c8 = (idx & 7) * 8;                           \
            *(uint4*)&As[row * SK + c8] =                                     \
                *(const uint4*)&Ah[(size_t)(tm * 128 + row) * F + k0 + c8];   \
        }                                                                     \
        _Pragma("unroll")                                                     \
        for (int c = 0; c < 2; ++c) {   /* B: 2x32 rows */                    \
            int idx = c * 256 + tid;                                          \
            int row = idx >> 3, c8 = (idx & 7) * 8;                           \
            *(uint4*)&Bs[row * SK + c8] =                                     \
                *(const uint4*)&Bh[(size_t)(tn * 64 + row) * F + k0 + c8];    \
        }                                                                     \
        __syncthreads();                                                      \
        _Pragma("unroll")                                                     \
        for (int s = 0; s < 2; ++s) {                                         \
            half8 a[2], b[4];                                                 \
            _Pragma("unroll")                                                 \
            for (int mt = 0; mt < 2; ++mt)                                    \
                a[mt] = *(const half8*)&As[(wid * 32 + mt * 16 + m16) * SK +  \
                                           s * 32 + q * 8];                   \
            _Pragma("unroll")                                                 \
            for (int nt = 0; nt < 4; ++nt)                                    \
                b[nt] = *(const half8*)&Bs[(nt * 16 + m16) * SK +             \
                                           s * 32 + q * 8];                   \
            _Pragma("unroll")                                                 \
            for (int mt = 0; mt < 2; ++mt)                                    \
                _Pragma("unroll")                                             \
                for (int nt = 0; nt < 4; ++nt)                                \
                    acc[mt][nt] = __builtin_amdgcn_mfma_f32_16x16x32_f16(     \
                        a[mt], b[nt], acc[mt][nt], 0, 0, 0);                  \
        }                                                                     \
        __syncthreads();                                                      \
    }

// Phase 0: epilogue accumulates S[k,i] += sum_j exp2(exp2(t)) via DPP
// reduce + atomicAdd; f32x4 rA loads (R5-proven shape, mt in {0,1}).
__global__ __launch_bounds__(256, 5) void gemm_phase0(
    const _Float16* __restrict__ Ah, const _Float16* __restrict__ Bh,
    const float* __restrict__ rA, const float* __restrict__ cB,
    const float* __restrict__ prm, float* __restrict__ S)
{
    GEMM_BODY

    float g[8];
#pragma unroll
    for (int k = 0; k < 8; ++k) g[k] = prm[8 + k];   // uniform -> SGPR

    float colQ[8][4];
#pragma unroll
    for (int nt = 0; nt < 4; ++nt) {
        int colg = tn * 64 + nt * 16 + m16;
#pragma unroll
        for (int k = 0; k < 8; ++k) colQ[k][nt] = cB[k * R + colg];
    }

#pragma unroll
    for (int mt = 0; mt < 2; ++mt) {
        int rowb = tm * 128 + wid * 32 + mt * 16 + q * 4;   // 4-aligned
#pragma unroll
        for (int k = 0; k < 8; ++k) {
            f32x4 ra4 = *(const f32x4*)&rA[k * R + rowb];
#pragma unroll
            for (int r = 0; r < 4; ++r) {
                float t = 0.f;
#pragma unroll
                for (int nt = 0; nt < 4; ++nt) {
                    float tt = fmaf(g[k], acc[mt][nt][r], ra4[r] + colQ[k][nt]);
                    t += __builtin_amdgcn_exp2f(__builtin_amdgcn_exp2f(tt));
                }
                t = dpp_radd<0xB1>(t);    // quad_perm xor1
                t = dpp_radd<0x4E>(t);    // quad_perm xor2
                t = dpp_radd<0x124>(t);   // row_ror:4
                t = dpp_radd<0x128>(t);   // row_ror:8
                if (m16 == 0) atomicAdd(&S[k * R + rowb + r], t);
            }
        }
    }
}

// Phase 1: epilogue finalizes out[i,j] = sum_k w_k*rcp(S[k,i])*exp2(exp2(t)).
// EXACT R5 narrow shape (R7's k-outer vectorization regressed), mt in {0,1}.
__global__ __launch_bounds__(256, 5) void gemm_phase1(
    const _Float16* __restrict__ Ah, const _Float16* __restrict__ Bh,
    const float* __restrict__ rA, const float* __restrict__ cB,
    const float* __restrict__ prm, const float* __restrict__ S,
    float* __restrict__ out)
{
    GEMM_BODY

    float g[8], wv[8];
#pragma unroll
    for (int k = 0; k < 8; ++k) { g[k] = prm[8 + k]; wv[k] = prm[k]; }

    int colg[4];
    float colQ[8][4];
#pragma unroll
    for (int nt = 0; nt < 4; ++nt) {
        colg[nt] = tn * 64 + nt * 16 + m16;
#pragma unroll
        for (int k = 0; k < 8; ++k) colQ[k][nt] = cB[k * R + colg[nt]];
    }

#pragma unroll
    for (int mt = 0; mt < 2; ++mt) {
#pragma unroll
        for (int r = 0; r < 4; ++r) {
            int rowg = tm * 128 + wid * 32 + mt * 16 + q * 4 + r;
            float rAv[8];
#pragma unroll
            for (int k = 0; k < 8; ++k) rAv[k] = rA[k * R + rowg];
            float sv[8];
#pragma unroll
            for (int k = 0; k < 8; ++k)
                sv[k] = wv[k] * __builtin_amdgcn_rcpf(S[k * R + rowg]);
#pragma unroll
            for (int nt = 0; nt < 4; ++nt) {
                float d = acc[mt][nt][r];
                float o = 0.f;
#pragma unroll
                for (int k = 0; k < 8; ++k) {
                    float tt = fmaf(g[k], d, rAv[k] + colQ[k][nt]);
                    o = fmaf(sv[k], __builtin_amdgcn_exp2f(__builtin_amdgcn_exp2f(tt)), o);
                }
                out[(size_t)rowg * R + colg[nt]] = o;
            }
        }
    }
}

extern "C" void kernel_launch(void* const* d_in, const int* in_sizes, int n_in,
                              void* d_out, int out_size, void* d_ws, size_t ws_size,
                              hipStream_t stream) {
    (void)in_sizes; (void)n_in; (void)out_size; (void)ws_size;
    const float* x1     = (const float*)d_in[0];
    const float* x2     = (const float*)d_in[1];
    const float* sigmas = (const float*)d_in[2];
    const float* means  = (const float*)d_in[3];
    const float* sigp   = (const float*)d_in[4];
    float* out = (float*)d_out;

    char* ws = (char*)d_ws;
    _Float16* x1h = (_Float16*)ws;
    _Float16* x2h = (_Float16*)(ws + 2097152);
    float* S   = (float*)(ws + 4194304);
    float* rA  = (float*)(ws + 4194304 + 131072);
    float* cB  = (float*)(ws + 4194304 + 262144);
    float* prm = (float*)(ws + 4194304 + 393216);

    prep_kernel<<<2048, 256, 0, stream>>>(x1, x2, sigmas, means, sigp,
                                          x1h, x2h, rA, cB, S, prm);
    gemm_phase0<<<dim3(64, 32), 256, 0, stream>>>(x1h, x2h, rA, cB, prm, S);
    gemm_phase1<<<dim3(64, 32), 256, 0, stream>>>(x1h, x2h, rA, cB, prm, S, out);
}

// Round 11
// 210.565 us; speedup vs baseline: 1.3571x; 1.3571x over previous
//
#include <hip/hip_runtime.h>
#include <cmath>

// Shapes fixed by reference: R=4096, F=256, K=8.
#define R 4096
#define F 256
#define NK 8

typedef _Float16 half8 __attribute__((ext_vector_type(8)));
typedef _Float16 half4v __attribute__((ext_vector_type(4)));
typedef float f32x4 __attribute__((ext_vector_type(4)));

#define LOG2E      1.4426950408889634f
#define LOG2LOG2E  0.5287663729448977f   // log2(log2(e))

// ---------------------------------------------------------------------------
// ws layout (bytes):
//   0          : x1h (4096*256 f16) 2 MB
//   2 MB       : x2h (4096*256 f16) 2 MB
//   4 MB +0    : S   (8*4096 f32)  softmax denominators (phase-0 atomics)
//       +128K  : rA  (8*4096 f32)  c_k*(sq1-2m r1+Fm^2)+log2log2e
//       +256K  : cB  (8*4096 f32)  c_k*(sq2+2m r2)
//       +384K  : prm (16 f32) [0..7]=w_k  [8..15]=g_k = 2*is2*log2e
// Math: c_k = -log2e/(2 s_k^2); t = rA[k][i]+cB[k][j]+g_k*dot,  g_k = -2 c_k
//       exp(kv) = exp2(exp2(t)).  dist in [~150,~6600] so ref clamps never bind.
//
// Structure: two-GEMM. R11: SAME 1024-block 128x128-tile footprint as R5
// (L2 sweet spot: 131 MB demand -> 10 MB FETCH), but 512-thread blocks =
// 8 waves of 32x64, acc[2][4]=32 AGPR -> unified ~88-96 regs -> 2 blocks/CU
// = 4 waves/SIMD (2x R5's occupancy) with identical per-block memory.
// FAILED -- do not reintroduce:
//  * cooperative grid.sync fusion (R1): +380 MB HBM spin/coherence traffic.
//  * dot spill through `out` (R2/R4): 64 MB writes back to HBM either way.
//  * NT stores (R2): write-drain stall, +29us.
//  * global_load_lds staging (R6): +16 VGPR -> occupancy cliff at 256thr.
//  * phase1 epilogue k-outer vectorization (R7): +7us (live-set growth).
//  * XCD block swizzle (R9): FETCH unchanged, +3us. Not cache-miss-bound.
//  * 128x64 tile / 2048 blocks (R10): grid growth broke L2 absorption --
//    FETCH 10->232 MB, WRITE 33->368 MB, phase1 60->163us. Keep grid=1024
//    and per-block demand = 128 KB.
// ---------------------------------------------------------------------------

__global__ __launch_bounds__(256) void prep_kernel(
    const float* __restrict__ x1, const float* __restrict__ x2,
    const float* __restrict__ sigmas, const float* __restrict__ means,
    const float* __restrict__ sigp,
    _Float16* __restrict__ x1h, _Float16* __restrict__ x2h,
    float* __restrict__ rA, float* __restrict__ cB,
    float* __restrict__ S, float* __restrict__ prm)
{
    const int tid  = threadIdx.x;
    const int wid  = tid >> 6;
    const int lane = tid & 63;
    const int row  = blockIdx.x * 4 + wid;   // 0..8191: x1 rows then x2 rows

    const float* src; _Float16* dsth; int r; bool isX1;
    if (row < R) { src = x1; dsth = x1h; r = row;     isX1 = true;  }
    else         { src = x2; dsth = x2h; r = row - R; isX1 = false; }

    float4 v = ((const float4*)(src + (size_t)r * F))[lane];
    half4v h = { (_Float16)v.x, (_Float16)v.y, (_Float16)v.z, (_Float16)v.w };
    *(half4v*)(dsth + (size_t)r * F + lane * 4) = h;

    float s = v.x + v.y + v.z + v.w;
    float q = v.x * v.x + v.y * v.y + v.z * v.z + v.w * v.w;
    for (int m = 1; m < 64; m <<= 1) {
        s += __shfl_xor(s, m);
        q += __shfl_xor(q, m);
    }
    if (lane < NK) {
        int k = lane;
        float sg = sigmas[k], m = means[k];
        float c  = -LOG2E / (2.f * sg * sg);         // c_k
        if (isX1) rA[k * R + r] = c * (q - 2.f * m * s + (float)F * m * m) + LOG2LOG2E;
        else      cB[k * R + r] = c * (q + 2.f * m * s);
    }

    int g = blockIdx.x * 256 + tid;
    if (g < NK * R) S[g] = 0.f;   // ws re-poisoned 0xAA each call

    if (blockIdx.x == 0 && tid == 0) {
        float w[NK], mx = -1e30f;
        for (int k = 0; k < NK; ++k) { float sp = sigp[k]; w[k] = 1.f / (sp * sp); mx = fmaxf(mx, w[k]); }
        float sum = 0.f;
        for (int k = 0; k < NK; ++k) { w[k] = expf(w[k] - mx); sum += w[k]; }
        for (int k = 0; k < NK; ++k) prm[k] = w[k] / sum;
        for (int k = 0; k < NK; ++k) {
            float sg = sigmas[k];
            prm[8 + k] = LOG2E / (sg * sg);     // g_k = 2*is2*log2e
        }
    }
}

// DPP-fused add: x + dpp_move(x, CTRL). CTRL must be an ICE -> template arg.
// Folds to v_add_f32_dpp (full-rate VALU, no lgkm). Verified bit-identical
// to the shfl reduce (R4/R5).
template <int CTRL>
__device__ __forceinline__ float dpp_radd(float x) {
    int xi = __builtin_bit_cast(int, x);
    int yi = __builtin_amdgcn_update_dpp(0, xi, CTRL, 0xF, 0xF, true);
    return x + __builtin_bit_cast(float, yi);
}

// ---------------------------------------------------------------------------
// Shared GEMM body (R11): 128x128 tile, 512 threads = 8 waves (4 wm x 2 wn),
// each wave owns a 32x64 quadrant strip; acc[2][4] = 32 f32/thread.
// Reg-staged LDS, SK=72 pad (2-way alias, free). Same per-block A/B demand
// and LDS (36.9KB) as R5.
// ---------------------------------------------------------------------------
#define GEMM_BODY                                                             \
    constexpr int SK = 72;                                                    \
    __shared__ _Float16 As[128 * SK];                                         \
    __shared__ _Float16 Bs[128 * SK];                                         \
    const int tid  = threadIdx.x;                                             \
    const int lane = tid & 63;                                                \
    const int wid  = tid >> 6;                 /* 0..7 */                     \
    const int wm   = wid >> 1, wn = wid & 1;   /* 4x2 waves of 32x64 */       \
    const int q    = lane >> 4, m16 = lane & 15;                              \
    const int tm   = blockIdx.y, tn = blockIdx.x;                             \
    f32x4 acc[2][4];                                                          \
    _Pragma("unroll")                                                         \
    for (int a = 0; a < 2; ++a)                                               \
        _Pragma("unroll")                                                     \
        for (int b = 0; b < 4; ++b)                                           \
            acc[a][b] = (f32x4){0.f, 0.f, 0.f, 0.f};                          \
    for (int k0 = 0; k0 < F; k0 += 64) {                                      \
        _Pragma("unroll")                                                     \
        for (int c = 0; c < 2; ++c) {                                         \
            int idx = c * 512 + tid;        /* 0..1023 chunks of 8 halves */  \
            int row = idx >> 3, c8 = (idx & 7) * 8;                           \
            *(uint4*)&As[row * SK + c8] =                                     \
                *(const uint4*)&Ah[(size_t)(tm * 128 + row) * F + k0 + c8];   \
            *(uint4*)&Bs[row * SK + c8] =                                     \
                *(const uint4*)&Bh[(size_t)(tn * 128 + row) * F + k0 + c8];   \
        }                                                                     \
        __syncthreads();                                                      \
        _Pragma("unroll")                                                     \
        for (int s = 0; s < 2; ++s) {                                         \
            half8 a[2], b[4];                                                 \
            _Pragma("unroll")                                                 \
            for (int mt = 0; mt < 2; ++mt)                                    \
                a[mt] = *(const half8*)&As[(wm * 32 + mt * 16 + m16) * SK +   \
                                           s * 32 + q * 8];                   \
            _Pragma("unroll")                                                 \
            for (int nt = 0; nt < 4; ++nt)                                    \
                b[nt] = *(const half8*)&Bs[(wn * 64 + nt * 16 + m16) * SK +   \
                                           s * 32 + q * 8];                   \
            _Pragma("unroll")                                                 \
            for (int mt = 0; mt < 2; ++mt)                                    \
                _Pragma("unroll")                                             \
                for (int nt = 0; nt < 4; ++nt)                                \
                    acc[mt][nt] = __builtin_amdgcn_mfma_f32_16x16x32_f16(     \
                        a[mt], b[nt], acc[mt][nt], 0, 0, 0);                  \
        }                                                                     \
        __syncthreads();                                                      \
    }

// Phase 0: epilogue accumulates S[k,i] += sum_j exp2(exp2(t)) via DPP
// reduce + atomicAdd; f32x4 rA loads. Same per-S[k,i] addend partition as
// R5 (32 tn-blocks x 2 wn-waves) -> same numerics.
__global__ __launch_bounds__(512, 4) void gemm_phase0(
    const _Float16* __restrict__ Ah, const _Float16* __restrict__ Bh,
    const float* __restrict__ rA, const float* __restrict__ cB,
    const float* __restrict__ prm, float* __restrict__ S)
{
    GEMM_BODY

    float g[8];
#pragma unroll
    for (int k = 0; k < 8; ++k) g[k] = prm[8 + k];   // uniform -> SGPR

    float colQ[8][4];
#pragma unroll
    for (int nt = 0; nt < 4; ++nt) {
        int colg = tn * 128 + wn * 64 + nt * 16 + m16;
#pragma unroll
        for (int k = 0; k < 8; ++k) colQ[k][nt] = cB[k * R + colg];
    }

#pragma unroll
    for (int mt = 0; mt < 2; ++mt) {
        int rowb = tm * 128 + wm * 32 + mt * 16 + q * 4;   // 4-aligned
#pragma unroll
        for (int k = 0; k < 8; ++k) {
            f32x4 ra4 = *(const f32x4*)&rA[k * R + rowb];
#pragma unroll
            for (int r = 0; r < 4; ++r) {
                float t = 0.f;
#pragma unroll
                for (int nt = 0; nt < 4; ++nt) {
                    float tt = fmaf(g[k], acc[mt][nt][r], ra4[r] + colQ[k][nt]);
                    t += __builtin_amdgcn_exp2f(__builtin_amdgcn_exp2f(tt));
                }
                t = dpp_radd<0xB1>(t);    // quad_perm xor1
                t = dpp_radd<0x4E>(t);    // quad_perm xor2
                t = dpp_radd<0x124>(t);   // row_ror:4
                t = dpp_radd<0x128>(t);   // row_ror:8
                if (m16 == 0) atomicAdd(&S[k * R + rowb + r], t);
            }
        }
    }
}

// Phase 1: epilogue finalizes out[i,j] = sum_k w_k*rcp(S[k,i])*exp2(exp2(t)).
// EXACT R5 narrow per-thread shape, mt in {0,1}.
__global__ __launch_bounds__(512, 4) void gemm_phase1(
    const _Float16* __restrict__ Ah, const _Float16* __restrict__ Bh,
    const float* __restrict__ rA, const float* __restrict__ cB,
    const float* __restrict__ prm, const float* __restrict__ S,
    float* __restrict__ out)
{
    GEMM_BODY

    float g[8], wv[8];
#pragma unroll
    for (int k = 0; k < 8; ++k) { g[k] = prm[8 + k]; wv[k] = prm[k]; }

    int colg[4];
    float colQ[8][4];
#pragma unroll
    for (int nt = 0; nt < 4; ++nt) {
        colg[nt] = tn * 128 + wn * 64 + nt * 16 + m16;
#pragma unroll
        for (int k = 0; k < 8; ++k) colQ[k][nt] = cB[k * R + colg[nt]];
    }

#pragma unroll
    for (int mt = 0; mt < 2; ++mt) {
#pragma unroll
        for (int r = 0; r < 4; ++r) {
            int rowg = tm * 128 + wm * 32 + mt * 16 + q * 4 + r;
            float rAv[8];
#pragma unroll
            for (int k = 0; k < 8; ++k) rAv[k] = rA[k * R + rowg];
            float sv[8];
#pragma unroll
            for (int k = 0; k < 8; ++k)
                sv[k] = wv[k] * __builtin_amdgcn_rcpf(S[k * R + rowg]);
#pragma unroll
            for (int nt = 0; nt < 4; ++nt) {
                float d = acc[mt][nt][r];
                float o = 0.f;
#pragma unroll
                for (int k = 0; k < 8; ++k) {
                    float tt = fmaf(g[k], d, rAv[k] + colQ[k][nt]);
                    o = fmaf(sv[k], __builtin_amdgcn_exp2f(__builtin_amdgcn_exp2f(tt)), o);
                }
                out[(size_t)rowg * R + colg[nt]] = o;
            }
        }
    }
}

extern "C" void kernel_launch(void* const* d_in, const int* in_sizes, int n_in,
                              void* d_out, int out_size, void* d_ws, size_t ws_size,
                              hipStream_t stream) {
    (void)in_sizes; (void)n_in; (void)out_size; (void)ws_size;
    const float* x1     = (const float*)d_in[0];
    const float* x2     = (const float*)d_in[1];
    const float* sigmas = (const float*)d_in[2];
    const float* means  = (const float*)d_in[3];
    const float* sigp   = (const float*)d_in[4];
    float* out = (float*)d_out;

    char* ws = (char*)d_ws;
    _Float16* x1h = (_Float16*)ws;
    _Float16* x2h = (_Float16*)(ws + 2097152);
    float* S   = (float*)(ws + 4194304);
    float* rA  = (float*)(ws + 4194304 + 131072);
    float* cB  = (float*)(ws + 4194304 + 262144);
    float* prm = (float*)(ws + 4194304 + 393216);

    prep_kernel<<<2048, 256, 0, stream>>>(x1, x2, sigmas, means, sigp,
                                          x1h, x2h, rA, cB, S, prm);
    gemm_phase0<<<dim3(32, 32), 512, 0, stream>>>(x1h, x2h, rA, cB, prm, S);
    gemm_phase1<<<dim3(32, 32), 512, 0, stream>>>(x1h, x2h, rA, cB, prm, S, out);
}

// Round 12
// 174.087 us; speedup vs baseline: 1.6415x; 1.2095x over previous
//
#include <hip/hip_runtime.h>
#include <cmath>

// Shapes fixed by reference: R=4096, F=256, K=8.
#define R 4096
#define F 256
#define NK 8

typedef _Float16 half8 __attribute__((ext_vector_type(8)));
typedef _Float16 half4v __attribute__((ext_vector_type(4)));
typedef float f32x4 __attribute__((ext_vector_type(4)));

#define LOG2E      1.4426950408889634f
#define LOG2LOG2E  0.5287663729448977f   // log2(log2(e))

// ---------------------------------------------------------------------------
// ws layout (bytes):
//   0          : x1h (4096*256 f16) 2 MB
//   2 MB       : x2h (4096*256 f16) 2 MB
//   4 MB +0    : S   (8*4096 f32)  softmax denominators (phase-0 atomics)
//       +128K  : rA  (8*4096 f32)  c_k*(sq1-2m r1+Fm^2)+log2log2e
//       +256K  : cB  (8*4096 f32)  c_k*(sq2+2m r2)
//       +384K  : prm (16 f32) [0..7]=w_k  [8..15]=g_k = 2*is2*log2e
// Math: c_k = -log2e/(2 s_k^2); t = rA[k][i]+cB[k][j]+g_k*dot,  g_k = -2 c_k
//       exp(kv) = exp2(exp2(t)).  dist in [~150,~6600] so ref clamps never bind.
//
// FINAL (R12): exact R5 configuration -- best measured 174.7us. Two-GEMM,
// 128x128 tile, 1024 blocks, 256 threads (4 waves of 64x64), acc[4][4]=64
// AGPR + 64 arch VGPR = 128 unified = 4 waves/SIMD, 4 blocks/CU, LDS 36.9KB.
// Phase 0: S via DPP-reduce + atomics, f32x4 rA loads. Phase 1: finalize.
// This point is a measured local optimum; the full failure ledger:
//  * cooperative grid.sync fusion (R1): +380 MB HBM spin/coherence traffic.
//  * dot spill through `out`, NT or cached (R2/R4): 64 MB write stream
//    evicts L2, finalize saves nothing vs the GEMM redo.
//  * NT stores (R2): write-drain stall, +29us.
//  * global_load_lds staging (R6): +16 VGPR -> 3 waves/SIMD, -11us. Bank
//    conflicts are a non-issue here (2-way alias free; 1e6->0 worth ~0).
//  * phase1 k-outer load vectorization (R7): +7us (live-set growth).
//  * XCD block swizzle (R9): FETCH unchanged (already L2-absorbed), +3us.
//  * 128x64 tile / 2048 blocks (R10): broke L2 absorption, FETCH 10->232MB.
//  * 512-thread 8-wave blocks (R11): +17us/phase (barrier overhead per
//    useful FLOP doubled; R5 was already at 4 waves/SIMD, not 2).
// Structural floor: per phase ~25us GEMM section (4-step K, barrier-locked)
// + ~35us epilogue (1024 exp2/thread, trans-floor ~14us + dep stalls).
// ---------------------------------------------------------------------------

__global__ __launch_bounds__(256) void prep_kernel(
    const float* __restrict__ x1, const float* __restrict__ x2,
    const float* __restrict__ sigmas, const float* __restrict__ means,
    const float* __restrict__ sigp,
    _Float16* __restrict__ x1h, _Float16* __restrict__ x2h,
    float* __restrict__ rA, float* __restrict__ cB,
    float* __restrict__ S, float* __restrict__ prm)
{
    const int tid  = threadIdx.x;
    const int wid  = tid >> 6;
    const int lane = tid & 63;
    const int row  = blockIdx.x * 4 + wid;   // 0..8191: x1 rows then x2 rows

    const float* src; _Float16* dsth; int r; bool isX1;
    if (row < R) { src = x1; dsth = x1h; r = row;     isX1 = true;  }
    else         { src = x2; dsth = x2h; r = row - R; isX1 = false; }

    float4 v = ((const float4*)(src + (size_t)r * F))[lane];
    half4v h = { (_Float16)v.x, (_Float16)v.y, (_Float16)v.z, (_Float16)v.w };
    *(half4v*)(dsth + (size_t)r * F + lane * 4) = h;

    float s = v.x + v.y + v.z + v.w;
    float q = v.x * v.x + v.y * v.y + v.z * v.z + v.w * v.w;
    for (int m = 1; m < 64; m <<= 1) {
        s += __shfl_xor(s, m);
        q += __shfl_xor(q, m);
    }
    if (lane < NK) {
        int k = lane;
        float sg = sigmas[k], m = means[k];
        float c  = -LOG2E / (2.f * sg * sg);         // c_k
        if (isX1) rA[k * R + r] = c * (q - 2.f * m * s + (float)F * m * m) + LOG2LOG2E;
        else      cB[k * R + r] = c * (q + 2.f * m * s);
    }

    int g = blockIdx.x * 256 + tid;
    if (g < NK * R) S[g] = 0.f;   // ws re-poisoned 0xAA each call

    if (blockIdx.x == 0 && tid == 0) {
        float w[NK], mx = -1e30f;
        for (int k = 0; k < NK; ++k) { float sp = sigp[k]; w[k] = 1.f / (sp * sp); mx = fmaxf(mx, w[k]); }
        float sum = 0.f;
        for (int k = 0; k < NK; ++k) { w[k] = expf(w[k] - mx); sum += w[k]; }
        for (int k = 0; k < NK; ++k) prm[k] = w[k] / sum;
        for (int k = 0; k < NK; ++k) {
            float sg = sigmas[k];
            prm[8 + k] = LOG2E / (sg * sg);     // g_k = 2*is2*log2e
        }
    }
}

// DPP-fused add: x + dpp_move(x, CTRL). CTRL must be an ICE -> template arg.
// Folds to v_add_f32_dpp (full-rate VALU, no lgkm). Verified bit-identical
// to the shfl reduce (R4/R5).
template <int CTRL>
__device__ __forceinline__ float dpp_radd(float x) {
    int xi = __builtin_bit_cast(int, x);
    int yi = __builtin_amdgcn_update_dpp(0, xi, CTRL, 0xF, 0xF, true);
    return x + __builtin_bit_cast(float, yi);
}

// ---------------------------------------------------------------------------
// Shared GEMM body (R5-proven): 128x128-tile fp16 MFMA, reg-staged LDS with
// SK=72 pad (row stride 144 B = 16B-aligned, 2-way bank alias = free).
// ---------------------------------------------------------------------------
#define GEMM_BODY                                                             \
    constexpr int SK = 72;                                                    \
    __shared__ _Float16 As[128 * SK];                                         \
    __shared__ _Float16 Bs[128 * SK];                                         \
    const int tid  = threadIdx.x;                                             \
    const int lane = tid & 63;                                                \
    const int wid  = tid >> 6;                                                \
    const int wm   = wid >> 1, wn = wid & 1;   /* 2x2 waves of 64x64 */       \
    const int q    = lane >> 4, m16 = lane & 15;                              \
    const int tm   = blockIdx.y, tn = blockIdx.x;                             \
    f32x4 acc[4][4];                                                          \
    _Pragma("unroll")                                                         \
    for (int a = 0; a < 4; ++a)                                               \
        _Pragma("unroll")                                                     \
        for (int b = 0; b < 4; ++b)                                           \
            acc[a][b] = (f32x4){0.f, 0.f, 0.f, 0.f};                          \
    for (int k0 = 0; k0 < F; k0 += 64) {                                      \
        _Pragma("unroll")                                                     \
        for (int c = 0; c < 4; ++c) {                                         \
            int idx = c * 256 + tid;        /* 0..1023 chunks of 8 halves */  \
            int row = idx >> 3, c8 = (idx & 7) * 8;                           \
            *(uint4*)&As[row * SK + c8] =                                     \
                *(const uint4*)&Ah[(size_t)(tm * 128 + row) * F + k0 + c8];   \
            *(uint4*)&Bs[row * SK + c8] =                                     \
                *(const uint4*)&Bh[(size_t)(tn * 128 + row) * F + k0 + c8];   \
        }                                                                     \
        __syncthreads();                                                      \
        _Pragma("unroll")                                                     \
        for (int s = 0; s < 2; ++s) {                                         \
            half8 a[4], b[4];                                                 \
            _Pragma("unroll")                                                 \
            for (int mt = 0; mt < 4; ++mt)                                    \
                a[mt] = *(const half8*)&As[(wm * 64 + mt * 16 + m16) * SK +   \
                                           s * 32 + q * 8];                   \
            _Pragma("unroll")                                                 \
            for (int nt = 0; nt < 4; ++nt)                                    \
                b[nt] = *(const half8*)&Bs[(wn * 64 + nt * 16 + m16) * SK +   \
                                           s * 32 + q * 8];                   \
            _Pragma("unroll")                                                 \
            for (int mt = 0; mt < 4; ++mt)                                    \
                _Pragma("unroll")                                             \
                for (int nt = 0; nt < 4; ++nt)                                \
                    acc[mt][nt] = __builtin_amdgcn_mfma_f32_16x16x32_f16(     \
                        a[mt], b[nt], acc[mt][nt], 0, 0, 0);                  \
        }                                                                     \
        __syncthreads();                                                      \
    }

// Phase 0: epilogue accumulates S[k,i] += sum_j exp2(exp2(t)) via DPP
// reduce + atomicAdd; f32x4 rA loads (R5-proven, unchanged).
__global__ __launch_bounds__(256, 2) void gemm_phase0(
    const _Float16* __restrict__ Ah, const _Float16* __restrict__ Bh,
    const float* __restrict__ rA, const float* __restrict__ cB,
    const float* __restrict__ prm, float* __restrict__ S)
{
    GEMM_BODY

    float g[8];
#pragma unroll
    for (int k = 0; k < 8; ++k) g[k] = prm[8 + k];   // uniform -> SGPR

    float colQ[8][4];
#pragma unroll
    for (int nt = 0; nt < 4; ++nt) {
        int colg = tn * 128 + wn * 64 + nt * 16 + m16;
#pragma unroll
        for (int k = 0; k < 8; ++k) colQ[k][nt] = cB[k * R + colg];
    }

#pragma unroll
    for (int mt = 0; mt < 4; ++mt) {
        int rowb = tm * 128 + wm * 64 + mt * 16 + q * 4;   // 4-aligned
#pragma unroll
        for (int k = 0; k < 8; ++k) {
            f32x4 ra4 = *(const f32x4*)&rA[k * R + rowb];
#pragma unroll
            for (int r = 0; r < 4; ++r) {
                float t = 0.f;
#pragma unroll
                for (int nt = 0; nt < 4; ++nt) {
                    float tt = fmaf(g[k], acc[mt][nt][r], ra4[r] + colQ[k][nt]);
                    t += __builtin_amdgcn_exp2f(__builtin_amdgcn_exp2f(tt));
                }
                t = dpp_radd<0xB1>(t);    // quad_perm xor1
                t = dpp_radd<0x4E>(t);    // quad_perm xor2
                t = dpp_radd<0x124>(t);   // row_ror:4
                t = dpp_radd<0x128>(t);   // row_ror:8
                if (m16 == 0) atomicAdd(&S[k * R + rowb + r], t);
            }
        }
    }
}

// Phase 1: epilogue finalizes out[i,j] = sum_k w_k*rcp(S[k,i])*exp2(exp2(t)).
// EXACT R5 narrow per-thread shape (R7's k-outer vectorization regressed).
__global__ __launch_bounds__(256, 2) void gemm_phase1(
    const _Float16* __restrict__ Ah, const _Float16* __restrict__ Bh,
    const float* __restrict__ rA, const float* __restrict__ cB,
    const float* __restrict__ prm, const float* __restrict__ S,
    float* __restrict__ out)
{
    GEMM_BODY

    float g[8], wv[8];
#pragma unroll
    for (int k = 0; k < 8; ++k) { g[k] = prm[8 + k]; wv[k] = prm[k]; }

    int colg[4];
    float colQ[8][4];
#pragma unroll
    for (int nt = 0; nt < 4; ++nt) {
        colg[nt] = tn * 128 + wn * 64 + nt * 16 + m16;
#pragma unroll
        for (int k = 0; k < 8; ++k) colQ[k][nt] = cB[k * R + colg[nt]];
    }

#pragma unroll
    for (int mt = 0; mt < 4; ++mt) {
#pragma unroll
        for (int r = 0; r < 4; ++r) {
            int rowg = tm * 128 + wm * 64 + mt * 16 + q * 4 + r;
            float rAv[8];
#pragma unroll
            for (int k = 0; k < 8; ++k) rAv[k] = rA[k * R + rowg];
            float sv[8];
#pragma unroll
            for (int k = 0; k < 8; ++k)
                sv[k] = wv[k] * __builtin_amdgcn_rcpf(S[k * R + rowg]);
#pragma unroll
            for (int nt = 0; nt < 4; ++nt) {
                float d = acc[mt][nt][r];
                float o = 0.f;
#pragma unroll
                for (int k = 0; k < 8; ++k) {
                    float tt = fmaf(g[k], d, rAv[k] + colQ[k][nt]);
                    o = fmaf(sv[k], __builtin_amdgcn_exp2f(__builtin_amdgcn_exp2f(tt)), o);
                }
                out[(size_t)rowg * R + colg[nt]] = o;
            }
        }
    }
}

extern "C" void kernel_launch(void* const* d_in, const int* in_sizes, int n_in,
                              void* d_out, int out_size, void* d_ws, size_t ws_size,
                              hipStream_t stream) {
    (void)in_sizes; (void)n_in; (void)out_size; (void)ws_size;
    const float* x1     = (const float*)d_in[0];
    const float* x2     = (const float*)d_in[1];
    const float* sigmas = (const float*)d_in[2];
    const float* means  = (const float*)d_in[3];
    const float* sigp   = (const float*)d_in[4];
    float* out = (float*)d_out;

    char* ws = (char*)d_ws;
    _Float16* x1h = (_Float16*)ws;
    _Float16* x2h = (_Float16*)(ws + 2097152);
    float* S   = (float*)(ws + 4194304);
    float* rA  = (float*)(ws + 4194304 + 131072);
    float* cB  = (float*)(ws + 4194304 + 262144);
    float* prm = (float*)(ws + 4194304 + 393216);

    prep_kernel<<<2048, 256, 0, stream>>>(x1, x2, sigmas, means, sigp,
                                          x1h, x2h, rA, cB, S, prm);
    gemm_phase0<<<dim3(32, 32), 256, 0, stream>>>(x1h, x2h, rA, cB, prm, S);
    gemm_phase1<<<dim3(32, 32), 256, 0, stream>>>(x1h, x2h, rA, cB, prm, S, out);
}